// Round 4
// baseline (182.528 us; speedup 1.0000x reference)
//
#include <hip/hip_runtime.h>
#include <hip/hip_bf16.h>
#include <stdint.h>

#define N_TOK 8192
#define D_K   1024
#define BM    256
#define BN    256
#define BK    32
#define NT    (D_K / BK)            // 32 K-tiles
#define TILE_E (BM * BK)            // 8192 elems = 16 KB per operand tile

typedef __attribute__((ext_vector_type(8))) short bf16x8;
typedef __attribute__((ext_vector_type(4))) float f32x4;

__global__ void zero_out_kernel(float* out) { out[0] = 0.0f; }

__device__ __forceinline__ unsigned short f32_to_bf16_rne(float x) {
  uint32_t u = __builtin_bit_cast(uint32_t, x);
  uint32_t r = (u >> 16) & 1u;
  u += 0x7fffu + r;
  return (unsigned short)(u >> 16);
}

__global__ void __launch_bounds__(256)
convert_kernel(const float* __restrict__ a, const float* __restrict__ b,
               ushort* __restrict__ oa, ushort* __restrict__ ob) {
  const size_t total4 = (size_t)N_TOK * D_K / 4;
  size_t i = (size_t)blockIdx.x * blockDim.x + threadIdx.x;
  size_t stride = (size_t)gridDim.x * blockDim.x;
  for (; i < total4; i += stride) {
    float4 va = ((const float4*)a)[i];
    float4 vb = ((const float4*)b)[i];
    ushort4 ua, ub;
    ua.x = f32_to_bf16_rne(va.x); ua.y = f32_to_bf16_rne(va.y);
    ua.z = f32_to_bf16_rne(va.z); ua.w = f32_to_bf16_rne(va.w);
    ub.x = f32_to_bf16_rne(vb.x); ub.y = f32_to_bf16_rne(vb.y);
    ub.z = f32_to_bf16_rne(vb.z); ub.w = f32_to_bf16_rne(vb.w);
    ((ushort4*)oa)[i] = ua;
    ((ushort4*)ob)[i] = ub;
  }
}

// Fused 256x256 bf16 MFMA GEMM + sigmoid-contrastive loss.
// BK=32, 4-deep LDS ring per operand (4 x 16 KB), stage distance 3.
// 2 phases per K-tile: {ds_read frags + issue gloads -> barrier -> 16 MFMA}.
// Counted vmcnt(8) once per tile (T4); setprio around MFMA (T5); XCD swizzle
// (T1); XOR slot swizzle slot^=(row>>1)&3 on both stage-source and read (T2).
__global__ void __launch_bounds__(512)
sigc_kernel(const ushort* __restrict__ A, const ushort* __restrict__ B,
            const int* __restrict__ labA, const int* __restrict__ labB,
            const float* __restrict__ scale_p, const float* __restrict__ bias_p,
            float* __restrict__ out) {
  __shared__ ushort sA[4 * TILE_E];   // 64 KB
  __shared__ ushort sB[4 * TILE_E];   // 64 KB
  __shared__ int sLabA[BM];
  __shared__ int sLabB[BN];
  __shared__ float sPart[8];

  const int tid  = threadIdx.x;
  const int lane = tid & 63;
  const int wid  = tid >> 6;      // 0..7
  const int wr   = wid >> 2;      // 0..1 (M half)
  const int wc   = wid & 3;       // 0..3 (N quarter)
  const int lr   = lane & 15;
  const int sHi  = lane >> 4;     // 0..3 (16B slot)

  // XCD-aware block swizzle: grid = 1024 (divisible by 8).
  const int bid  = (int)blockIdx.x;
  const int swzb = (bid & 7) * 128 + (bid >> 3);
  const int bRow = (swzb >> 5) * BM;
  const int bCol = (swzb & 31) * BN;

  if (tid < 256) sLabA[tid] = labA[bRow + tid];
  else           sLabB[tid - 256] = labB[bCol + (tid - 256)];

  // Staging geometry: tile = 256 rows x 32 cols; 2 issues of 512thr x 16B.
  // Linear LDS dest; source column swizzled (rule #21).
  int sgRow[2], sgCol[2];
#pragma unroll
  for (int i = 0; i < 2; ++i) {
    const int e    = i * 4096 + tid * 8;
    const int row  = e >> 5;
    const int slot = (e >> 3) & 3;
    sgRow[i] = row;
    sgCol[i] = (slot ^ ((row >> 1) & 3)) << 3;
  }
  const int ldsOff0 = wid * 512;
  const int ldsOff1 = 4096 + wid * 512;

  auto stageA = [&](int tt) {
    ushort* d = sA + (tt & 3) * TILE_E;
    const ushort* g0 = A + (size_t)(bRow + sgRow[0]) * D_K + tt * BK + sgCol[0];
    const ushort* g1 = A + (size_t)(bRow + sgRow[1]) * D_K + tt * BK + sgCol[1];
    __builtin_amdgcn_global_load_lds(
        (const __attribute__((address_space(1))) void*)g0,
        (__attribute__((address_space(3))) void*)(d + ldsOff0), 16, 0, 0);
    __builtin_amdgcn_global_load_lds(
        (const __attribute__((address_space(1))) void*)g1,
        (__attribute__((address_space(3))) void*)(d + ldsOff1), 16, 0, 0);
  };
  auto stageB = [&](int tt) {
    ushort* d = sB + (tt & 3) * TILE_E;
    const ushort* g0 = B + (size_t)(bCol + sgRow[0]) * D_K + tt * BK + sgCol[0];
    const ushort* g1 = B + (size_t)(bCol + sgRow[1]) * D_K + tt * BK + sgCol[1];
    __builtin_amdgcn_global_load_lds(
        (const __attribute__((address_space(1))) void*)g0,
        (__attribute__((address_space(3))) void*)(d + ldsOff0), 16, 0, 0);
    __builtin_amdgcn_global_load_lds(
        (const __attribute__((address_space(1))) void*)g1,
        (__attribute__((address_space(3))) void*)(d + ldsOff1), 16, 0, 0);
  };

  f32x4 acc[2][4][4];
#pragma unroll
  for (int q = 0; q < 2; ++q)
#pragma unroll
    for (int i = 0; i < 4; ++i)
#pragma unroll
      for (int j = 0; j < 4; ++j) acc[q][i][j] = (f32x4){0.f, 0.f, 0.f, 0.f};

  // Prologue: stage tiles 0..2, full drain once (also publishes labels).
  stageA(0); stageB(0);
  stageA(1); stageB(1);
  stageA(2); stageB(2);
  __syncthreads();

  for (int t = 0; t < NT; ++t) {
    const ushort* bufA = sA + (t & 3) * TILE_E;
    const ushort* bufB = sB + (t & 3) * TILE_E;

    // ---- phase A: frag reads (8) + stage A(t+3) -> barrier -> 16 MFMA ----
    bf16x8 af[4], bf[4];
#pragma unroll
    for (int mi = 0; mi < 4; ++mi) {
      const int r = wr * 128 + mi * 16 + lr;
      af[mi] = *(const bf16x8*)&bufA[r * BK + ((sHi ^ ((r >> 1) & 3)) << 3)];
    }
#pragma unroll
    for (int ni = 0; ni < 4; ++ni) {
      const int r = wc * 64 + ni * 16 + lr;
      bf[ni] = *(const bf16x8*)&bufB[r * BK + ((sHi ^ ((r >> 1) & 3)) << 3)];
    }
    if (t <= NT - 4) stageA(t + 3);
    __builtin_amdgcn_sched_barrier(0);
    __builtin_amdgcn_s_barrier();
    __builtin_amdgcn_sched_barrier(0);
    __builtin_amdgcn_s_setprio(1);
#pragma unroll
    for (int mi = 0; mi < 4; ++mi)
#pragma unroll
      for (int ni = 0; ni < 4; ++ni)
        acc[0][mi][ni] = __builtin_amdgcn_mfma_f32_16x16x32_bf16(
            af[mi], bf[ni], acc[0][mi][ni], 0, 0, 0);
    __builtin_amdgcn_s_setprio(0);

    // ---- phase B: frag reads (4) + stage B(t+3) -> barrier -> 16 MFMA ----
    bf16x8 ag[4];
#pragma unroll
    for (int mi = 0; mi < 4; ++mi) {
      const int r = wr * 128 + 64 + mi * 16 + lr;
      ag[mi] = *(const bf16x8*)&bufA[r * BK + ((sHi ^ ((r >> 1) & 3)) << 3)];
    }
    if (t <= NT - 4) stageB(t + 3);
    __builtin_amdgcn_sched_barrier(0);
    __builtin_amdgcn_s_barrier();
    __builtin_amdgcn_sched_barrier(0);
    __builtin_amdgcn_s_setprio(1);
#pragma unroll
    for (int mi = 0; mi < 4; ++mi)
#pragma unroll
      for (int ni = 0; ni < 4; ++ni)
        acc[1][mi][ni] = __builtin_amdgcn_mfma_f32_16x16x32_bf16(
            ag[mi], bf[ni], acc[1][mi][ni], 0, 0, 0);
    __builtin_amdgcn_s_setprio(0);

    // ---- tile boundary: counted vmcnt (retire t+1), barrier ----
    if (t < NT - 1) {
      if (t <= NT - 4)      asm volatile("s_waitcnt vmcnt(8)" ::: "memory");
      else if (t == NT - 3) asm volatile("s_waitcnt vmcnt(4)" ::: "memory");
      else                  asm volatile("s_waitcnt vmcnt(0)" ::: "memory");
      __builtin_amdgcn_sched_barrier(0);
      __builtin_amdgcn_s_barrier();
      __builtin_amdgcn_sched_barrier(0);
    }
  }

  // Epilogue: -log_sigmoid(label*logit) = max(t,0) + log(1+exp(-|t|)).
  const float scale = scale_p[0];
  const float bias  = bias_p[0];
  float loss = 0.0f;
  const int cBase = lane & 15;
  const int rBase = (lane >> 4) * 4;
#pragma unroll
  for (int mh = 0; mh < 2; ++mh) {
#pragma unroll
    for (int mi = 0; mi < 4; ++mi) {
#pragma unroll
      for (int ni = 0; ni < 4; ++ni) {
        const int colL = sLabB[wc * 64 + ni * 16 + cBase];
#pragma unroll
        for (int r = 0; r < 4; ++r) {
          const int rowL = sLabA[wr * 128 + mh * 64 + mi * 16 + rBase + r];
          const float logit = fmaf(scale, acc[mh][mi][ni][r], bias);
          const float tt = (rowL == colL) ? -logit : logit;
          loss += fmaxf(tt, 0.0f) + __logf(1.0f + __expf(-fabsf(tt)));
        }
      }
    }
  }

#pragma unroll
  for (int off = 32; off > 0; off >>= 1) loss += __shfl_down(loss, off, 64);
  if (lane == 0) sPart[wid] = loss;
  __syncthreads();
  if (tid == 0) {
    float s = 0.f;
#pragma unroll
    for (int w = 0; w < 8; ++w) s += sPart[w];
    atomicAdd(out, s * (1.0f / (float)N_TOK));
  }
}

extern "C" void kernel_launch(void* const* d_in, const int* in_sizes, int n_in,
                              void* d_out, int out_size, void* d_ws, size_t ws_size,
                              hipStream_t stream) {
  const float* a  = (const float*)d_in[0];
  const float* b  = (const float*)d_in[1];
  const int*   la = (const int*)d_in[2];
  const int*   lb = (const int*)d_in[3];
  const float* sc = (const float*)d_in[4];
  const float* bi = (const float*)d_in[5];
  float* out = (float*)d_out;

  ushort* wa = (ushort*)d_ws;                       // bf16 A, 16 MB
  ushort* wb = wa + (size_t)N_TOK * D_K;            // bf16 B, 16 MB

  zero_out_kernel<<<1, 1, 0, stream>>>(out);
  convert_kernel<<<2048, 256, 0, stream>>>(a, b, wa, wb);
  const int grid = (N_TOK / BM) * (N_TOK / BN);     // 1024
  sigc_kernel<<<grid, 512, 0, stream>>>(wa, wb, la, lb, sc, bi, out);
}